// Round 4
// baseline (464.395 us; speedup 1.0000x reference)
//
#include <hip/hip_runtime.h>
#include <hip/hip_bf16.h>

#define N_ 8
#define C_ 256
#define HW_ 4096
#define CNT_ (C_*HW_)

typedef __attribute__((ext_vector_type(8))) short bf16x8;
typedef __attribute__((ext_vector_type(4))) float f32x4;
typedef __attribute__((ext_vector_type(16))) float f32x16;

__device__ inline float exp2fast(float x){ return __builtin_amdgcn_exp2f(x); }

__device__ inline unsigned short f2bf(float f){
  union{float f; unsigned u;} v; v.f=f;
  unsigned r = v.u + 0x7fff + ((v.u>>16)&1);
  return (unsigned short)(r>>16);
}

__device__ inline f32x4 mfma16(bf16x8 a, bf16x8 b, f32x4 c){
  return __builtin_amdgcn_mfma_f32_16x16x32_bf16(a,b,c,0,0,0);
}
__device__ inline f32x16 mfma32(bf16x8 a, bf16x8 b, f32x16 c){
  return __builtin_amdgcn_mfma_f32_32x32x16_bf16(a,b,c,0,0,0);
}

#define GLL16(gp, lp) __builtin_amdgcn_global_load_lds( \
    (__attribute__((address_space(1))) void*)(gp), \
    (__attribute__((address_space(3))) void*)(lp), 16, 0, 0)

// ---------------- weight convert (fp32 -> bf16) ----------------
__global__ void k_cvt(const float* __restrict__ src, unsigned short* __restrict__ dst){
  int i = blockIdx.x*256 + threadIdx.x;
  dst[i] = f2bf(src[i]);
}

// ---------------- layernorm stats, stage 1 ----------------
__global__ void k_stats1(const float* __restrict__ x, float2* __restrict__ part){
  int n = blockIdx.x >> 8;
  int chunk = blockIdx.x & 255;
  const float4* p = (const float4*)(x + (size_t)n*CNT_ + (size_t)chunk*4096);
  int t = threadIdx.x;
  float s=0.f, s2=0.f;
  #pragma unroll
  for(int i=0;i<4;i++){
    float4 v = p[t + 256*i];
    s  += v.x+v.y+v.z+v.w;
    s2 += v.x*v.x+v.y*v.y+v.z*v.z+v.w*v.w;
  }
  #pragma unroll
  for(int o=32;o;o>>=1){ s += __shfl_down(s,o); s2 += __shfl_down(s2,o); }
  __shared__ float sh[4], sh2[4];
  int lane = t&63, wid = t>>6;
  if(lane==0){ sh[wid]=s; sh2[wid]=s2; }
  __syncthreads();
  if(t==0){
    float2 r; r.x = sh[0]+sh[1]+sh[2]+sh[3]; r.y = sh2[0]+sh2[1]+sh2[2]+sh2[3];
    part[blockIdx.x] = r;
  }
}

// ---------------- layernorm stats, stage 2 ----------------
__global__ void k_stats2(const float2* __restrict__ part, float2* __restrict__ stats){
  int n = blockIdx.x, t = threadIdx.x;
  float2 v = part[n*256 + t];
  float s = v.x, s2 = v.y;
  #pragma unroll
  for(int o=32;o;o>>=1){ s += __shfl_down(s,o); s2 += __shfl_down(s2,o); }
  __shared__ float sh[4], sh2[4];
  int lane = t&63, wid = t>>6;
  if(lane==0){ sh[wid]=s; sh2[wid]=s2; }
  __syncthreads();
  if(t==0){
    s = sh[0]+sh[1]+sh[2]+sh[3];
    s2 = sh2[0]+sh2[1]+sh2[2]+sh2[3];
    float mean = s * (1.f/(float)CNT_);
    float var  = s2 * (1.f/(float)CNT_) - mean*mean;
    float2 r; r.x = mean; r.y = rsqrtf(var + 1e-5f);
    stats[n] = r;
  }
}

// ---------------- normalize + transpose to NHWC bf16 ----------------
__global__ void k_norm(const float* __restrict__ x, const float* __restrict__ lnw,
                       const float* __restrict__ lnb, const float2* __restrict__ stats,
                       unsigned short* __restrict__ nx){
  __shared__ float tile[64][65];
  int n = blockIdx.z, c0 = blockIdx.y*64, p0 = blockIdx.x*64;
  float2 st = stats[n];
  float mu = st.x, rs = st.y;
  int t = threadIdx.x, col = t&63, rw = t>>6;
  #pragma unroll
  for(int pass=0; pass<16; pass++){
    int row = pass*4 + rw;
    size_t gi = (size_t)(c0+row)*HW_ + (p0+col);
    float v = x[(size_t)n*CNT_ + gi];
    tile[row][col] = (v - mu)*rs*lnw[gi] + lnb[gi];
  }
  __syncthreads();
  #pragma unroll
  for(int pass=0; pass<16; pass++){
    int prow = pass*4 + rw;
    nx[((size_t)n*HW_ + p0+prow)*C_ + c0 + col] = f2bf(tile[col][prow]);
  }
}

// ---------------- strip GEMM: D[row][col] = (sum_k A[row][k]*B[col][k] + bias)*scale ----
__global__ void k_gemm(const unsigned short* __restrict__ Abase, long strideA,
                       const unsigned short* __restrict__ Bbase, long strideB,
                       const float* __restrict__ bias, int bias_row, float scale,
                       unsigned short* __restrict__ Out, long strideO, int ldo){
  int n = blockIdx.z;
  const unsigned short* A = Abase + (size_t)n*strideA;
  const unsigned short* B = Bbase + (size_t)n*strideB;
  unsigned short* O = Out + (size_t)n*strideO;
  int t = threadIdx.x, w = t>>6, l = t&63, ri = l&15, k8 = (l>>4)*8;
  int row0 = blockIdx.x*64 + w*16;
  int col0 = blockIdx.y*64;
  f32x4 zero = {0.f,0.f,0.f,0.f};
  f32x4 acc[4] = {zero, zero, zero, zero};
  for(int k=0;k<256;k+=32){
    bf16x8 a = *(const bf16x8*)(A + (size_t)(row0+ri)*256 + k + k8);
    #pragma unroll
    for(int j=0;j<4;j++){
      bf16x8 b = *(const bf16x8*)(B + (size_t)(col0+j*16+ri)*256 + k + k8);
      acc[j] = mfma16(a,b,acc[j]);
    }
  }
  #pragma unroll
  for(int j=0;j<4;j++){
    #pragma unroll
    for(int r=0;r<4;r++){
      int row = row0 + (l>>4)*4 + r;
      int col = col0 + j*16 + ri;
      float d = (acc[j][r] + (bias_row ? bias[row] : bias[col]))*scale;
      O[(size_t)row*ldo + col] = f2bf(d);
    }
  }
}

// ---------------- flash attention, counted-vmcnt 2-phase schedule ----------------
// 256 blocks x 512 threads. 8 waves = 2 j-streams x 4 q-strips (32 q each).
// K LDS: [stream][buf][32 rows x 512B], XOR-slot swizzled
// V LDS: [stream][buf][256 rows x 80B]
__device__ inline void stage_K(const char* kb, char* lds, int w, int l, int itx, int buf){
  int hi = l>>5, lo5 = l&31;
  #pragma unroll
  for(int k=0;k<4;k++){
    int g = w*4+k, s = g>>4, i = g&15;
    int row = 2*i + hi;
    int j = s*2048 + itx*32 + row;
    const char* src = kb + ((size_t)j<<9) + (((lo5 ^ row)&31)<<4);
    char* dst = lds + ((s*2+buf)<<14) + (i<<10);
    GLL16(src, dst);
  }
}
__device__ inline void stage_V(const char* vb, char* lds, int w, int l, int itx, int buf){
  #pragma unroll
  for(int k=0;k<5;k++){
    int g = w*5+k; int s = (g>=20) ? 1 : 0; int i = g - s*20;
    int c = i*64 + l;
    int d = c/5; int sg = c - d*5; if(sg==4) sg=0;
    int j0 = s*2048 + itx*32;
    const char* src = vb + ((size_t)d<<13) + ((size_t)j0<<1) + (sg<<4);
    char* dst = lds + 65536 + (s*2+buf)*20480 + i*1024;
    GLL16(src, dst);
  }
}

__global__ __launch_bounds__(512, 2) void k_attn3(const unsigned short* __restrict__ qt,
                                                  const unsigned short* __restrict__ kt,
                                                  const unsigned short* __restrict__ vv,
                                                  unsigned short* __restrict__ rest){
  __shared__ __align__(16) char lds[147456];
  int t = threadIdx.x, w = t>>6, l = t&63, hi = l>>5, lo5 = l&31;
  int nb = blockIdx.x & 7, qb = blockIdx.x >> 3;
  int st = w & 3, sm = w >> 2;
  int q0 = qb*128 + st*32;
  const char* kb = (const char*)(kt + (size_t)nb*HW_*C_);
  const char* vb = (const char*)(vv + (size_t)nb*C_*HW_);
  const char* qp = (const char*)(qt + (size_t)nb*HW_*C_);

  bf16x8 qf[16];
  #pragma unroll
  for(int ds=0; ds<16; ds++)
    qf[ds] = *(const bf16x8*)(qp + ((size_t)(q0+lo5)<<9) + ds*32 + hi*16);

  f32x16 o[8];
  #pragma unroll
  for(int dt=0;dt<8;dt++){
    #pragma unroll
    for(int r=0;r<16;r++) o[dt][r]=0.f;
  }
  float m = -1e30f, lsum = 0.f;

  // prologue: stage tile 0 into buf 0 (4 K + 5 V gll per wave in flight)
  stage_K(kb, lds, w, l, 0, 0);
  stage_V(vb, lds, w, l, 0, 0);

  for(int it=0; it<64; ++it){
    int cur = it & 1;
    int nxt = (it+1) & 63;          // wrap: uniform vmcnt counts; stray loads drained after loop
    // ---- K phase ----
    stage_K(kb, lds, w, l, nxt, cur^1);
    asm volatile("s_waitcnt vmcnt(9)" ::: "memory");  // drain old K (4), keep 9 in flight
    __builtin_amdgcn_s_barrier();
    const char* Kc = lds + ((sm*2+cur)<<14);
    const char* Vc = lds + 65536 + (sm*2+cur)*20480;

    // QK^T : S[j][q], lane holds q = lo5 (swapped operands); 2 chains to break dep serialization
    f32x16 S0, S1;
    #pragma unroll
    for(int r=0;r<16;r++){ S0[r]=0.f; S1[r]=0.f; }
    __builtin_amdgcn_s_setprio(1);
    #pragma unroll
    for(int ds=0; ds<8; ds++){
      bf16x8 kf0 = *(const bf16x8*)(Kc + (lo5<<9) + ((((4*ds)|hi) ^ lo5)<<4));
      bf16x8 kf1 = *(const bf16x8*)(Kc + (lo5<<9) + ((((4*ds+2)|hi) ^ lo5)<<4));
      S0 = mfma32(kf0, qf[2*ds], S0);
      S1 = mfma32(kf1, qf[2*ds+1], S1);
    }
    __builtin_amdgcn_s_setprio(0);

    // ---- V phase ----
    stage_V(vb, lds, w, l, nxt, cur^1);
    asm volatile("s_waitcnt vmcnt(9)" ::: "memory");  // drain old V (5), keep 9 in flight
    __builtin_amdgcn_s_barrier();

    f32x16 S;
    #pragma unroll
    for(int r=0;r<16;r++) S[r] = S0[r] + S1[r];

    // online softmax (base-2; Q pre-scaled by log2e/16)
    float mx = fmaxf(S[0], S[1]);
    #pragma unroll
    for(int r=2;r<16;r++) mx = fmaxf(mx, S[r]);
    mx = fmaxf(mx, __shfl_xor(mx, 32));
    if (!__all(mx <= m + 11.5f)){
      float mn = fmaxf(m, mx);
      float al = exp2fast(m - mn);
      lsum *= al;
      #pragma unroll
      for(int dt=0;dt<8;dt++) o[dt] = o[dt] * al;
      m = mn;
    }
    unsigned pk[8];
    float rs = 0.f;
    #pragma unroll
    for(int tt=0;tt<8;tt++){
      float pa = exp2fast(S[2*tt]-m), pb = exp2fast(S[2*tt+1]-m);
      rs += pa + pb;
      unsigned pr;
      asm("v_cvt_pk_bf16_f32 %0, %1, %2" : "=v"(pr) : "v"(pa), "v"(pb));
      pk[tt] = pr;
    }
    rs += __shfl_xor(rs, 32);
    lsum += rs;

    // build PV A-operand fragments from lane-local P via cross-half shuffle
    unsigned xk[8];
    #pragma unroll
    for(int tt=0;tt<8;tt++) xk[tt] = (unsigned)__shfl_xor((int)pk[tt], 32);
    bool hb = (l & 32) != 0;
    union { unsigned u[4]; bf16x8 v; } F0, F1;
    F0.u[0] = hb ? xk[2] : pk[0];
    F0.u[1] = hb ? xk[3] : pk[1];
    F0.u[2] = hb ? pk[2] : xk[0];
    F0.u[3] = hb ? pk[3] : xk[1];
    F1.u[0] = hb ? xk[6] : pk[4];
    F1.u[1] = hb ? xk[7] : pk[5];
    F1.u[2] = hb ? pk[6] : xk[4];
    F1.u[3] = hb ? pk[7] : xk[5];

    // PV: O^T[d][q] += V[d][j] * P[q][j]
    __builtin_amdgcn_s_setprio(1);
    #pragma unroll
    for(int dt=0;dt<8;dt++){
      bf16x8 v0 = *(const bf16x8*)(Vc + (dt*32+lo5)*80 + hi*16);
      o[dt] = mfma32(v0, F0.v, o[dt]);
      bf16x8 v1 = *(const bf16x8*)(Vc + (dt*32+lo5)*80 + 32 + hi*16);
      o[dt] = mfma32(v1, F1.v, o[dt]);
    }
    __builtin_amdgcn_s_setprio(0);
    // no barrier here: next iter's K-phase barrier protects buffer reuse
  }

  // drain stray wrap-around prefetch before reusing LDS as scratch
  asm volatile("s_waitcnt vmcnt(0)" ::: "memory");
  __syncthreads();

  // in-block merge of the two j-streams, then write rest[q][d] bf16
  float* mlf = (float*)(lds + 133120);
  if (sm == 1){
    char* base = lds + st*33280 + lo5*1040;
    #pragma unroll
    for(int dt=0;dt<8;dt++){
      #pragma unroll
      for(int g=0;g<4;g++){
        float4 v4; v4.x=o[dt][4*g]; v4.y=o[dt][4*g+1]; v4.z=o[dt][4*g+2]; v4.w=o[dt][4*g+3];
        *(float4*)(base + (dt*32 + g*8 + hi*4)*4) = v4;
      }
    }
    if (l < 32){ mlf[st*64 + lo5] = m; mlf[st*64 + 32 + lo5] = lsum; }
  }
  __syncthreads();
  if (sm == 0){
    float m1 = mlf[st*64 + lo5], l1 = mlf[st*64 + 32 + lo5];
    float mN = fmaxf(m, m1);
    float a0 = exp2fast(m - mN), a1 = exp2fast(m1 - mN);
    float inv = 1.f/(lsum*a0 + l1*a1);
    const char* base = lds + st*33280 + lo5*1040;
    unsigned short* rb = rest + ((size_t)nb*HW_ + q0 + lo5)*C_;
    #pragma unroll
    for(int dt=0;dt<8;dt++){
      #pragma unroll
      for(int g=0;g<4;g++){
        float4 o1 = *(const float4*)(base + (dt*32+g*8+hi*4)*4);
        int d0 = dt*32 + g*8 + hi*4;
        unsigned short h0 = f2bf((o[dt][4*g]*a0   + o1.x*a1)*inv);
        unsigned short h1 = f2bf((o[dt][4*g+1]*a0 + o1.y*a1)*inv);
        unsigned short h2 = f2bf((o[dt][4*g+2]*a0 + o1.z*a1)*inv);
        unsigned short h3 = f2bf((o[dt][4*g+3]*a0 + o1.w*a1)*inv);
        uint2 uo; uo.x = (unsigned)h0 | ((unsigned)h1<<16);
        uo.y = (unsigned)h2 | ((unsigned)h3<<16);
        *(uint2*)(rb + d0) = uo;
      }
    }
  }
}

// ---------------- output projection + residual (fp32 out) ----------------
__global__ void k_outproj(const unsigned short* __restrict__ wob,
                          const unsigned short* __restrict__ rest,
                          const float* __restrict__ bo, const float* __restrict__ x,
                          float* __restrict__ out){
  int n = blockIdx.z;
  const unsigned short* B = rest + (size_t)n*HW_*C_;
  int t = threadIdx.x, w = t>>6, l = t&63, ri = l&15, k8 = (l>>4)*8;
  int row0 = blockIdx.x*64 + w*16;
  int col0 = blockIdx.y*64;
  f32x4 zero = {0.f,0.f,0.f,0.f};
  f32x4 acc[4] = {zero, zero, zero, zero};
  for(int k=0;k<256;k+=32){
    bf16x8 a = *(const bf16x8*)(wob + (size_t)(row0+ri)*256 + k + k8);
    #pragma unroll
    for(int j=0;j<4;j++){
      bf16x8 b = *(const bf16x8*)(B + (size_t)(col0+j*16+ri)*256 + k + k8);
      acc[j] = mfma16(a,b,acc[j]);
    }
  }
  #pragma unroll
  for(int j=0;j<4;j++){
    #pragma unroll
    for(int r=0;r<4;r++){
      int row = row0 + (l>>4)*4 + r;
      int col = col0 + j*16 + ri;
      size_t idx = ((size_t)n*C_ + row)*HW_ + col;
      out[idx] = acc[j][r] + bo[row] + x[idx];
    }
  }
}

extern "C" void kernel_launch(void* const* d_in, const int* in_sizes, int n_in,
                              void* d_out, int out_size, void* d_ws, size_t ws_size,
                              hipStream_t stream) {
  const float* x   = (const float*)d_in[0];
  const float* lnw = (const float*)d_in[1];
  const float* lnb = (const float*)d_in[2];
  const float* wq  = (const float*)d_in[3];
  const float* bq  = (const float*)d_in[4];
  const float* wk  = (const float*)d_in[5];
  const float* bk  = (const float*)d_in[6];
  const float* wv  = (const float*)d_in[7];
  const float* bv  = (const float*)d_in[8];
  const float* wo  = (const float*)d_in[9];
  const float* bo  = (const float*)d_in[10];
  float* out = (float*)d_out;

  uintptr_t base = (uintptr_t)d_ws;
  float2* part  = (float2*)base;
  float2* stats = (float2*)(base + 16384);
  unsigned short* wqb = (unsigned short*)(base + 16448);
  unsigned short* wkb = wqb + 65536;
  unsigned short* wvb = wqb + 2*65536;
  unsigned short* wob = wqb + 3*65536;
  unsigned short* nx  = wqb + 4*65536;
  const size_t TEN = (size_t)N_*HW_*C_;
  unsigned short* qtb = nx + TEN;
  unsigned short* ktb = qtb + TEN;
  unsigned short* vvb = ktb + TEN;
  unsigned short* rest = nx;

  k_cvt<<<dim3(256),256,0,stream>>>(wq, wqb);
  k_cvt<<<dim3(256),256,0,stream>>>(wk, wkb);
  k_cvt<<<dim3(256),256,0,stream>>>(wv, wvb);
  k_cvt<<<dim3(256),256,0,stream>>>(wo, wob);

  k_stats1<<<dim3(2048),256,0,stream>>>(x, part);
  k_stats2<<<dim3(8),256,0,stream>>>(part, stats);
  k_norm<<<dim3(64,4,8),256,0,stream>>>(x, lnw, lnb, stats, nx);

  // Q pre-scaled by log2(e)/16 (softmax runs in base-2), K: [seq][dim]; V: [dim][seq]
  k_gemm<<<dim3(64,4,8),256,0,stream>>>(nx, (long)(HW_*C_), wqb, 0, bq, 0, 0.09016844f, qtb, (long)(HW_*C_), C_);
  k_gemm<<<dim3(64,4,8),256,0,stream>>>(nx, (long)(HW_*C_), wkb, 0, bk, 0, 1.0f, ktb, (long)(HW_*C_), C_);
  k_gemm<<<dim3(4,64,8),256,0,stream>>>(wvb, 0, nx, (long)(HW_*C_), bv, 1, 1.0f, vvb, (long)(C_*HW_), HW_);

  k_attn3<<<dim3(256),512,0,stream>>>(qtb, ktb, vvb, rest);

  k_outproj<<<dim3(4,64,8),256,0,stream>>>(wob, rest, bo, x, out);
}

// Round 5
// 409.717 us; speedup vs baseline: 1.1335x; 1.1335x over previous
//
#include <hip/hip_runtime.h>
#include <hip/hip_bf16.h>

#define N_ 8
#define C_ 256
#define HW_ 4096
#define CNT_ (C_*HW_)

typedef __attribute__((ext_vector_type(8))) short bf16x8;
typedef __attribute__((ext_vector_type(4))) float f32x4;
typedef __attribute__((ext_vector_type(16))) float f32x16;

__device__ inline float exp2fast(float x){ return __builtin_amdgcn_exp2f(x); }

__device__ inline unsigned short f2bf(float f){
  union{float f; unsigned u;} v; v.f=f;
  unsigned r = v.u + 0x7fff + ((v.u>>16)&1);
  return (unsigned short)(r>>16);
}
__device__ inline float bf2f(unsigned short h){
  union{unsigned u; float f;} v; v.u = ((unsigned)h)<<16; return v.f;
}

__device__ inline f32x4 mfma16(bf16x8 a, bf16x8 b, f32x4 c){
  return __builtin_amdgcn_mfma_f32_16x16x32_bf16(a,b,c,0,0,0);
}
__device__ inline f32x16 mfma32(bf16x8 a, bf16x8 b, f32x16 c){
  return __builtin_amdgcn_mfma_f32_32x32x16_bf16(a,b,c,0,0,0);
}

#define GLL16(gp, lp) __builtin_amdgcn_global_load_lds( \
    (__attribute__((address_space(1))) void*)(gp), \
    (__attribute__((address_space(3))) void*)(lp), 16, 0, 0)

// ---------------- weight convert (fp32 -> bf16) ----------------
__global__ void k_cvt(const float* __restrict__ src, unsigned short* __restrict__ dst){
  int i = blockIdx.x*256 + threadIdx.x;
  dst[i] = f2bf(src[i]);
}

// ---------------- layernorm stats, stage 1 ----------------
__global__ void k_stats1(const float* __restrict__ x, float2* __restrict__ part){
  int n = blockIdx.x >> 8;
  int chunk = blockIdx.x & 255;
  const float4* p = (const float4*)(x + (size_t)n*CNT_ + (size_t)chunk*4096);
  int t = threadIdx.x;
  float s=0.f, s2=0.f;
  #pragma unroll
  for(int i=0;i<4;i++){
    float4 v = p[t + 256*i];
    s  += v.x+v.y+v.z+v.w;
    s2 += v.x*v.x+v.y*v.y+v.z*v.z+v.w*v.w;
  }
  #pragma unroll
  for(int o=32;o;o>>=1){ s += __shfl_down(s,o); s2 += __shfl_down(s2,o); }
  __shared__ float sh[4], sh2[4];
  int lane = t&63, wid = t>>6;
  if(lane==0){ sh[wid]=s; sh2[wid]=s2; }
  __syncthreads();
  if(t==0){
    float2 r; r.x = sh[0]+sh[1]+sh[2]+sh[3]; r.y = sh2[0]+sh2[1]+sh2[2]+sh2[3];
    part[blockIdx.x] = r;
  }
}

// ---------------- layernorm stats, stage 2 ----------------
__global__ void k_stats2(const float2* __restrict__ part, float2* __restrict__ stats){
  int n = blockIdx.x, t = threadIdx.x;
  float2 v = part[n*256 + t];
  float s = v.x, s2 = v.y;
  #pragma unroll
  for(int o=32;o;o>>=1){ s += __shfl_down(s,o); s2 += __shfl_down(s2,o); }
  __shared__ float sh[4], sh2[4];
  int lane = t&63, wid = t>>6;
  if(lane==0){ sh[wid]=s; sh2[wid]=s2; }
  __syncthreads();
  if(t==0){
    s = sh[0]+sh[1]+sh[2]+sh[3];
    s2 = sh2[0]+sh2[1]+sh2[2]+sh2[3];
    float mean = s * (1.f/(float)CNT_);
    float var  = s2 * (1.f/(float)CNT_) - mean*mean;
    float2 r; r.x = mean; r.y = rsqrtf(var + 1e-5f);
    stats[n] = r;
  }
}

// ---------------- normalize + transpose to NHWC bf16 ----------------
__global__ void k_norm(const float* __restrict__ x, const float* __restrict__ lnw,
                       const float* __restrict__ lnb, const float2* __restrict__ stats,
                       unsigned short* __restrict__ nx){
  __shared__ float tile[64][65];
  int n = blockIdx.z, c0 = blockIdx.y*64, p0 = blockIdx.x*64;
  float2 st = stats[n];
  float mu = st.x, rs = st.y;
  int t = threadIdx.x, col = t&63, rw = t>>6;
  #pragma unroll
  for(int pass=0; pass<16; pass++){
    int row = pass*4 + rw;
    size_t gi = (size_t)(c0+row)*HW_ + (p0+col);
    float v = x[(size_t)n*CNT_ + gi];
    tile[row][col] = (v - mu)*rs*lnw[gi] + lnb[gi];
  }
  __syncthreads();
  #pragma unroll
  for(int pass=0; pass<16; pass++){
    int prow = pass*4 + rw;
    nx[((size_t)n*HW_ + p0+prow)*C_ + c0 + col] = f2bf(tile[col][prow]);
  }
}

// ---------------- strip GEMM: D[row][col] = (sum_k A[row][k]*B[col][k] + bias)*scale ----
__global__ void k_gemm(const unsigned short* __restrict__ Abase, long strideA,
                       const unsigned short* __restrict__ Bbase, long strideB,
                       const float* __restrict__ bias, int bias_row, float scale,
                       unsigned short* __restrict__ Out, long strideO, int ldo){
  int n = blockIdx.z;
  const unsigned short* A = Abase + (size_t)n*strideA;
  const unsigned short* B = Bbase + (size_t)n*strideB;
  unsigned short* O = Out + (size_t)n*strideO;
  int t = threadIdx.x, w = t>>6, l = t&63, ri = l&15, k8 = (l>>4)*8;
  int row0 = blockIdx.x*64 + w*16;
  int col0 = blockIdx.y*64;
  f32x4 zero = {0.f,0.f,0.f,0.f};
  f32x4 acc[4] = {zero, zero, zero, zero};
  for(int k=0;k<256;k+=32){
    bf16x8 a = *(const bf16x8*)(A + (size_t)(row0+ri)*256 + k + k8);
    #pragma unroll
    for(int j=0;j<4;j++){
      bf16x8 b = *(const bf16x8*)(B + (size_t)(col0+j*16+ri)*256 + k + k8);
      acc[j] = mfma16(a,b,acc[j]);
    }
  }
  #pragma unroll
  for(int j=0;j<4;j++){
    #pragma unroll
    for(int r=0;r<4;r++){
      int row = row0 + (l>>4)*4 + r;
      int col = col0 + j*16 + ri;
      float d = (acc[j][r] + (bias_row ? bias[row] : bias[col]))*scale;
      O[(size_t)row*ldo + col] = f2bf(d);
    }
  }
}

// ---------------- flash attention: 4-wave blocks, j-split across blocks ----------------
// 512 blocks x 256 threads. Block = (batch nb, q-tile of 128, j-half of 2048).
// Wave w owns q-strip of 32. K LDS [32][512B] XOR-swizzled; V LDS [256][80B]. 36 KB -> 2 blocks/CU.
// Writes unnormalized partial O (bf16) + (m,lsum); k_merge combines the two j-halves.
__global__ __launch_bounds__(256, 2) void k_attn4(const unsigned short* __restrict__ qt,
                                                  const unsigned short* __restrict__ kt,
                                                  const unsigned short* __restrict__ vv,
                                                  unsigned short* __restrict__ pO0,
                                                  unsigned short* __restrict__ pO1,
                                                  float2* __restrict__ pml){
  __shared__ __align__(16) char lds[36864];
  int t = threadIdx.x, w = t>>6, l = t&63, hi = l>>5, lo5 = l&31;
  int nb = blockIdx.x & 7, rem = blockIdx.x >> 3;
  int qb = rem >> 1, jh = rem & 1;
  int q0 = qb*128 + w*32;
  const char* kb = (const char*)(kt + (size_t)nb*HW_*C_);
  const char* vb = (const char*)(vv + (size_t)nb*C_*HW_);
  const char* qp = (const char*)(qt + (size_t)nb*HW_*C_);
  int jbase = jh*2048;

  bf16x8 qf[16];
  #pragma unroll
  for(int ds=0; ds<16; ds++)
    qf[ds] = *(const bf16x8*)(qp + ((size_t)(q0+lo5)<<9) + ds*32 + hi*16);

  f32x16 o[8];
  #pragma unroll
  for(int dt=0;dt<8;dt++){
    #pragma unroll
    for(int r=0;r<16;r++) o[dt][r]=0.f;
  }
  float m = -1e30f, lsum = 0.f;

  for(int it=0; it<64; ++it){
    int j0 = jbase + it*32;
    // stage K [32 rows][512B], slot-swizzled: LDS slot lo5 <- global d-slice (lo5^row)
    #pragma unroll
    for(int k=0;k<4;k++){
      int i = w*4+k;
      int row = 2*i + hi;
      GLL16(kb + ((size_t)(j0+row)<<9) + (((lo5^row)&31)<<4), lds + (i<<10));
    }
    // stage V [256 rows][80B: 64 data + 16 pad]
    #pragma unroll
    for(int k=0;k<5;k++){
      int g = w*5+k;
      int c = g*64 + l;
      int d = c/5; int sg = c - d*5; sg = (sg==4)?0:sg;
      GLL16(vb + ((size_t)d<<13) + ((size_t)j0<<1) + (sg<<4), lds + 16384 + (g<<10));
    }
    __syncthreads();   // vmcnt(0)+lgkmcnt(0) drain: tiles ready

    // QK^T: S[j][q], lane holds q=lo5 (swapped operands)
    f32x16 S;
    #pragma unroll
    for(int r=0;r<16;r++) S[r]=0.f;
    __builtin_amdgcn_s_setprio(1);
    #pragma unroll
    for(int ds=0; ds<16; ds++){
      bf16x8 kf = *(const bf16x8*)(lds + (lo5<<9) + ((((ds<<1)|hi)^lo5)<<4));
      S = mfma32(kf, qf[ds], S);
    }
    __builtin_amdgcn_s_setprio(0);

    // online softmax (base-2; Q pre-scaled by log2e/16)
    float mx = fmaxf(S[0], S[1]);
    #pragma unroll
    for(int r=2;r<16;r++) mx = fmaxf(mx, S[r]);
    mx = fmaxf(mx, __shfl_xor(mx, 32));
    if (!__all(mx <= m + 11.5f)){
      float mn = fmaxf(m, mx);
      float al = exp2fast(m - mn);
      lsum *= al;
      #pragma unroll
      for(int dt=0;dt<8;dt++) o[dt] = o[dt] * al;
      m = mn;
    }
    unsigned pk[8];
    float rs = 0.f;
    #pragma unroll
    for(int tt=0;tt<8;tt++){
      float pa = exp2fast(S[2*tt]-m), pb = exp2fast(S[2*tt+1]-m);
      rs += pa + pb;
      unsigned pr;
      asm("v_cvt_pk_bf16_f32 %0, %1, %2" : "=v"(pr) : "v"(pa), "v"(pb));
      pk[tt] = pr;
    }
    rs += __shfl_xor(rs, 32);
    lsum += rs;

    // build PV A-fragments from lane-local P via cross-half shuffle
    unsigned xk[8];
    #pragma unroll
    for(int tt=0;tt<8;tt++) xk[tt] = (unsigned)__shfl_xor((int)pk[tt], 32);
    bool hb = (l & 32) != 0;
    union { unsigned u[4]; bf16x8 v; } F0, F1;
    F0.u[0] = hb ? xk[2] : pk[0];
    F0.u[1] = hb ? xk[3] : pk[1];
    F0.u[2] = hb ? pk[2] : xk[0];
    F0.u[3] = hb ? pk[3] : xk[1];
    F1.u[0] = hb ? xk[6] : pk[4];
    F1.u[1] = hb ? xk[7] : pk[5];
    F1.u[2] = hb ? pk[6] : xk[4];
    F1.u[3] = hb ? pk[7] : xk[5];

    // PV: O^T[d][q] += V[d][j] * P[q][j]
    __builtin_amdgcn_s_setprio(1);
    #pragma unroll
    for(int dt=0;dt<8;dt++){
      bf16x8 v0 = *(const bf16x8*)(lds + 16384 + (dt*32+lo5)*80 + hi*16);
      o[dt] = mfma32(v0, F0.v, o[dt]);
      bf16x8 v1 = *(const bf16x8*)(lds + 16384 + (dt*32+lo5)*80 + 32 + hi*16);
      o[dt] = mfma32(v1, F1.v, o[dt]);
    }
    __builtin_amdgcn_s_setprio(0);
    __syncthreads();   // all reads done before next stage overwrites
  }

  // write unnormalized partial O (bf16) + (m, lsum)
  unsigned short* pb = (jh ? pO1 : pO0) + ((size_t)nb*HW_ + q0 + lo5)*C_;
  #pragma unroll
  for(int dt=0;dt<8;dt++){
    #pragma unroll
    for(int g=0;g<4;g++){
      int d0 = dt*32 + g*8 + hi*4;
      unsigned short h0 = f2bf(o[dt][4*g]);
      unsigned short h1 = f2bf(o[dt][4*g+1]);
      unsigned short h2 = f2bf(o[dt][4*g+2]);
      unsigned short h3 = f2bf(o[dt][4*g+3]);
      uint2 uo; uo.x = (unsigned)h0 | ((unsigned)h1<<16);
      uo.y = (unsigned)h2 | ((unsigned)h3<<16);
      *(uint2*)(pb + d0) = uo;
    }
  }
  if (l < 32){
    float2 ml; ml.x = m; ml.y = lsum;
    pml[(size_t)jh*32768 + (size_t)nb*HW_ + q0 + lo5] = ml;
  }
}

// ---------------- merge the two j-half partials (in place into pO0 = rest) ----------------
__global__ void k_merge(unsigned short* __restrict__ pO0,
                        const unsigned short* __restrict__ pO1,
                        const float2* __restrict__ pml){
  int t = threadIdx.x;
  int row = blockIdx.x*8 + (t>>5);
  int dn = t & 31;
  float2 ml0 = pml[row], ml1 = pml[32768 + row];
  float mN = fmaxf(ml0.x, ml1.x);
  float a0 = exp2fast(ml0.x - mN), a1 = exp2fast(ml1.x - mN);
  float inv = 1.f/(a0*ml0.y + a1*ml1.y);
  float s0 = a0*inv, s1 = a1*inv;
  size_t off = (size_t)row*256 + dn*8;
  uint4 u0 = *(const uint4*)(pO0 + off);
  uint4 u1 = *(const uint4*)(pO1 + off);
  unsigned r[4];
  unsigned w0[4] = {u0.x, u0.y, u0.z, u0.w};
  unsigned w1[4] = {u1.x, u1.y, u1.z, u1.w};
  #pragma unroll
  for(int q=0;q<4;q++){
    float lo = s0*bf2f((unsigned short)(w0[q]&0xffff)) + s1*bf2f((unsigned short)(w1[q]&0xffff));
    float hi = s0*bf2f((unsigned short)(w0[q]>>16))    + s1*bf2f((unsigned short)(w1[q]>>16));
    r[q] = (unsigned)f2bf(lo) | ((unsigned)f2bf(hi)<<16);
  }
  uint4 ru; ru.x=r[0]; ru.y=r[1]; ru.z=r[2]; ru.w=r[3];
  *(uint4*)(pO0 + off) = ru;
}

// ---------------- output projection + residual (fp32 out) ----------------
__global__ void k_outproj(const unsigned short* __restrict__ wob,
                          const unsigned short* __restrict__ rest,
                          const float* __restrict__ bo, const float* __restrict__ x,
                          float* __restrict__ out){
  int n = blockIdx.z;
  const unsigned short* B = rest + (size_t)n*HW_*C_;
  int t = threadIdx.x, w = t>>6, l = t&63, ri = l&15, k8 = (l>>4)*8;
  int row0 = blockIdx.x*64 + w*16;
  int col0 = blockIdx.y*64;
  f32x4 zero = {0.f,0.f,0.f,0.f};
  f32x4 acc[4] = {zero, zero, zero, zero};
  for(int k=0;k<256;k+=32){
    bf16x8 a = *(const bf16x8*)(wob + (size_t)(row0+ri)*256 + k + k8);
    #pragma unroll
    for(int j=0;j<4;j++){
      bf16x8 b = *(const bf16x8*)(B + (size_t)(col0+j*16+ri)*256 + k + k8);
      acc[j] = mfma16(a,b,acc[j]);
    }
  }
  #pragma unroll
  for(int j=0;j<4;j++){
    #pragma unroll
    for(int r=0;r<4;r++){
      int row = row0 + (l>>4)*4 + r;
      int col = col0 + j*16 + ri;
      size_t idx = ((size_t)n*C_ + row)*HW_ + col;
      out[idx] = acc[j][r] + bo[row] + x[idx];
    }
  }
}

extern "C" void kernel_launch(void* const* d_in, const int* in_sizes, int n_in,
                              void* d_out, int out_size, void* d_ws, size_t ws_size,
                              hipStream_t stream) {
  const float* x   = (const float*)d_in[0];
  const float* lnw = (const float*)d_in[1];
  const float* lnb = (const float*)d_in[2];
  const float* wq  = (const float*)d_in[3];
  const float* bq  = (const float*)d_in[4];
  const float* wk  = (const float*)d_in[5];
  const float* bk  = (const float*)d_in[6];
  const float* wv  = (const float*)d_in[7];
  const float* bv  = (const float*)d_in[8];
  const float* wo  = (const float*)d_in[9];
  const float* bo  = (const float*)d_in[10];
  float* out = (float*)d_out;

  uintptr_t base = (uintptr_t)d_ws;
  float2* part  = (float2*)base;
  float2* stats = (float2*)(base + 16384);
  unsigned short* wqb = (unsigned short*)(base + 16448);
  unsigned short* wkb = wqb + 65536;
  unsigned short* wvb = wqb + 2*65536;
  unsigned short* wob = wqb + 3*65536;
  unsigned short* nx  = wqb + 4*65536;
  const size_t TEN = (size_t)N_*HW_*C_;
  unsigned short* qtb = nx + TEN;
  unsigned short* ktb = qtb + TEN;
  unsigned short* vvb = ktb + TEN;
  unsigned short* pO1 = vvb + TEN;                 // extra 16 MB partial (j-half 1)
  float2* pml = (float2*)(pO1 + TEN);              // 2*32768 float2
  unsigned short* rest = nx;                       // = pO0 (j-half 0), merged in place

  k_cvt<<<dim3(256),256,0,stream>>>(wq, wqb);
  k_cvt<<<dim3(256),256,0,stream>>>(wk, wkb);
  k_cvt<<<dim3(256),256,0,stream>>>(wv, wvb);
  k_cvt<<<dim3(256),256,0,stream>>>(wo, wob);

  k_stats1<<<dim3(2048),256,0,stream>>>(x, part);
  k_stats2<<<dim3(8),256,0,stream>>>(part, stats);
  k_norm<<<dim3(64,4,8),256,0,stream>>>(x, lnw, lnb, stats, nx);

  // Q pre-scaled by log2(e)/16 (softmax runs in base-2), K: [seq][dim]; V: [dim][seq]
  k_gemm<<<dim3(64,4,8),256,0,stream>>>(nx, (long)(HW_*C_), wqb, 0, bq, 0, 0.09016844f, qtb, (long)(HW_*C_), C_);
  k_gemm<<<dim3(64,4,8),256,0,stream>>>(nx, (long)(HW_*C_), wkb, 0, bk, 0, 1.0f, ktb, (long)(HW_*C_), C_);
  k_gemm<<<dim3(4,64,8),256,0,stream>>>(wvb, 0, nx, (long)(HW_*C_), bv, 1, 1.0f, vvb, (long)(C_*HW_), HW_);

  k_attn4<<<dim3(512),256,0,stream>>>(qtb, ktb, vvb, rest, pO1, pml);
  k_merge<<<dim3(4096),256,0,stream>>>(rest, pO1, pml);

  k_outproj<<<dim3(4,64,8),256,0,stream>>>(wob, rest, bo, x, out);
}

// Round 6
// 402.813 us; speedup vs baseline: 1.1529x; 1.0171x over previous
//
#include <hip/hip_runtime.h>
#include <hip/hip_bf16.h>

#define N_ 8
#define C_ 256
#define HW_ 4096
#define CNT_ (C_*HW_)

typedef __attribute__((ext_vector_type(8))) short bf16x8;
typedef __attribute__((ext_vector_type(4))) float f32x4;
typedef __attribute__((ext_vector_type(16))) float f32x16;

__device__ inline float exp2fast(float x){ return __builtin_amdgcn_exp2f(x); }

__device__ inline unsigned short f2bf(float f){
  union{float f; unsigned u;} v; v.f=f;
  unsigned r = v.u + 0x7fff + ((v.u>>16)&1);
  return (unsigned short)(r>>16);
}
__device__ inline float bf2f(unsigned short h){
  union{unsigned u; float f;} v; v.u = ((unsigned)h)<<16; return v.f;
}

__device__ inline f32x4 mfma16(bf16x8 a, bf16x8 b, f32x4 c){
  return __builtin_amdgcn_mfma_f32_16x16x32_bf16(a,b,c,0,0,0);
}
__device__ inline f32x16 mfma32(bf16x8 a, bf16x8 b, f32x16 c){
  return __builtin_amdgcn_mfma_f32_32x32x16_bf16(a,b,c,0,0,0);
}

#define GLL16(gp, lp) __builtin_amdgcn_global_load_lds( \
    (__attribute__((address_space(1))) void*)(gp), \
    (__attribute__((address_space(3))) void*)(lp), 16, 0, 0)

// ---------------- weight convert (fp32 -> bf16) ----------------
__global__ void k_cvt(const float* __restrict__ src, unsigned short* __restrict__ dst){
  int i = blockIdx.x*256 + threadIdx.x;
  dst[i] = f2bf(src[i]);
}

// ---------------- layernorm stats, stage 1 ----------------
__global__ void k_stats1(const float* __restrict__ x, float2* __restrict__ part){
  int n = blockIdx.x >> 8;
  int chunk = blockIdx.x & 255;
  const float4* p = (const float4*)(x + (size_t)n*CNT_ + (size_t)chunk*4096);
  int t = threadIdx.x;
  float s=0.f, s2=0.f;
  #pragma unroll
  for(int i=0;i<4;i++){
    float4 v = p[t + 256*i];
    s  += v.x+v.y+v.z+v.w;
    s2 += v.x*v.x+v.y*v.y+v.z*v.z+v.w*v.w;
  }
  #pragma unroll
  for(int o=32;o;o>>=1){ s += __shfl_down(s,o); s2 += __shfl_down(s2,o); }
  __shared__ float sh[4], sh2[4];
  int lane = t&63, wid = t>>6;
  if(lane==0){ sh[wid]=s; sh2[wid]=s2; }
  __syncthreads();
  if(t==0){
    float2 r; r.x = sh[0]+sh[1]+sh[2]+sh[3]; r.y = sh2[0]+sh2[1]+sh2[2]+sh2[3];
    part[blockIdx.x] = r;
  }
}

// ---------------- layernorm stats, stage 2 ----------------
__global__ void k_stats2(const float2* __restrict__ part, float2* __restrict__ stats){
  int n = blockIdx.x, t = threadIdx.x;
  float2 v = part[n*256 + t];
  float s = v.x, s2 = v.y;
  #pragma unroll
  for(int o=32;o;o>>=1){ s += __shfl_down(s,o); s2 += __shfl_down(s2,o); }
  __shared__ float sh[4], sh2[4];
  int lane = t&63, wid = t>>6;
  if(lane==0){ sh[wid]=s; sh2[wid]=s2; }
  __syncthreads();
  if(t==0){
    s = sh[0]+sh[1]+sh[2]+sh[3];
    s2 = sh2[0]+sh2[1]+sh2[2]+sh2[3];
    float mean = s * (1.f/(float)CNT_);
    float var  = s2 * (1.f/(float)CNT_) - mean*mean;
    float2 r; r.x = mean; r.y = rsqrtf(var + 1e-5f);
    stats[n] = r;
  }
}

// ---------------- normalize + transpose to NHWC bf16 ----------------
__global__ void k_norm(const float* __restrict__ x, const float* __restrict__ lnw,
                       const float* __restrict__ lnb, const float2* __restrict__ stats,
                       unsigned short* __restrict__ nx){
  __shared__ float tile[64][65];
  int n = blockIdx.z, c0 = blockIdx.y*64, p0 = blockIdx.x*64;
  float2 st = stats[n];
  float mu = st.x, rs = st.y;
  int t = threadIdx.x, col = t&63, rw = t>>6;
  #pragma unroll
  for(int pass=0; pass<16; pass++){
    int row = pass*4 + rw;
    size_t gi = (size_t)(c0+row)*HW_ + (p0+col);
    float v = x[(size_t)n*CNT_ + gi];
    tile[row][col] = (v - mu)*rs*lnw[gi] + lnb[gi];
  }
  __syncthreads();
  #pragma unroll
  for(int pass=0; pass<16; pass++){
    int prow = pass*4 + rw;
    nx[((size_t)n*HW_ + p0+prow)*C_ + c0 + col] = f2bf(tile[col][prow]);
  }
}

// ---------------- strip GEMM: D[row][col] = (sum_k A[row][k]*B[col][k] + bias)*scale ----
__global__ void k_gemm(const unsigned short* __restrict__ Abase, long strideA,
                       const unsigned short* __restrict__ Bbase, long strideB,
                       const float* __restrict__ bias, int bias_row, float scale,
                       unsigned short* __restrict__ Out, long strideO, int ldo){
  int n = blockIdx.z;
  const unsigned short* A = Abase + (size_t)n*strideA;
  const unsigned short* B = Bbase + (size_t)n*strideB;
  unsigned short* O = Out + (size_t)n*strideO;
  int t = threadIdx.x, w = t>>6, l = t&63, ri = l&15, k8 = (l>>4)*8;
  int row0 = blockIdx.x*64 + w*16;
  int col0 = blockIdx.y*64;
  f32x4 zero = {0.f,0.f,0.f,0.f};
  f32x4 acc[4] = {zero, zero, zero, zero};
  #pragma unroll
  for(int k=0;k<256;k+=32){
    bf16x8 a = *(const bf16x8*)(A + (size_t)(row0+ri)*256 + k + k8);
    #pragma unroll
    for(int j=0;j<4;j++){
      bf16x8 b = *(const bf16x8*)(B + (size_t)(col0+j*16+ri)*256 + k + k8);
      acc[j] = mfma16(a,b,acc[j]);
    }
  }
  #pragma unroll
  for(int j=0;j<4;j++){
    #pragma unroll
    for(int r=0;r<4;r++){
      int row = row0 + (l>>4)*4 + r;
      int col = col0 + j*16 + ri;
      float d = (acc[j][r] + (bias_row ? bias[row] : bias[col]))*scale;
      O[(size_t)row*ldo + col] = f2bf(d);
    }
  }
}

// ---------------- flash attention: 4-wave blocks, j-split across blocks ----------------
// 512 blocks x 256 threads. Block = (batch nb, q-tile of 128, j-half of 2048).
// Wave w owns q-strip of 32. K LDS [32][512B] XOR-swizzled; V LDS [256][80B]. 36 KB.
// Cross-half exchanges all via v_permlane32_swap_b32 (VALU pipe) - no DS shuffles in loop.
__global__ __launch_bounds__(256, 2) void k_attn4(const unsigned short* __restrict__ qt,
                                                  const unsigned short* __restrict__ kt,
                                                  const unsigned short* __restrict__ vv,
                                                  unsigned short* __restrict__ pO0,
                                                  unsigned short* __restrict__ pO1,
                                                  float2* __restrict__ pml){
  __shared__ __align__(16) char lds[36864];
  int t = threadIdx.x, w = t>>6, l = t&63, hi = l>>5, lo5 = l&31;
  int nb = blockIdx.x & 7, rem = blockIdx.x >> 3;
  int qb = rem >> 1, jh = rem & 1;
  int q0 = qb*128 + w*32;
  const char* kb = (const char*)(kt + (size_t)nb*HW_*C_);
  const char* vb = (const char*)(vv + (size_t)nb*C_*HW_);
  const char* qp = (const char*)(qt + (size_t)nb*HW_*C_);
  int jbase = jh*2048;

  bf16x8 qf[16];
  #pragma unroll
  for(int ds=0; ds<16; ds++)
    qf[ds] = *(const bf16x8*)(qp + ((size_t)(q0+lo5)<<9) + ds*32 + hi*16);

  f32x16 o[8];
  #pragma unroll
  for(int dt=0;dt<8;dt++){
    #pragma unroll
    for(int r=0;r<16;r++) o[dt][r]=0.f;
  }
  float m = -1e30f, lsum = 0.f;

  for(int it=0; it<64; ++it){
    int j0 = jbase + it*32;
    // stage K [32 rows][512B], slot-swizzled: LDS slot lo5 <- global d-slice (lo5^row)
    #pragma unroll
    for(int k=0;k<4;k++){
      int i = w*4+k;
      int row = 2*i + hi;
      GLL16(kb + ((size_t)(j0+row)<<9) + (((lo5^row)&31)<<4), lds + (i<<10));
    }
    // stage V [256 rows][80B: 64 data + 16 pad]
    #pragma unroll
    for(int k=0;k<5;k++){
      int g = w*5+k;
      int c = g*64 + l;
      int d = c/5; int sg = c - d*5; sg = (sg==4)?0:sg;
      GLL16(vb + ((size_t)d<<13) + ((size_t)j0<<1) + (sg<<4), lds + 16384 + (g<<10));
    }
    __syncthreads();   // vmcnt(0)+lgkmcnt(0) drain: tiles ready

    // QK^T: S[j][q], lane holds q=lo5 (swapped operands)
    f32x16 S;
    #pragma unroll
    for(int r=0;r<16;r++) S[r]=0.f;
    __builtin_amdgcn_s_setprio(1);
    #pragma unroll
    for(int ds=0; ds<16; ds++){
      bf16x8 kf = *(const bf16x8*)(lds + (lo5<<9) + ((((ds<<1)|hi)^lo5)<<4));
      S = mfma32(kf, qf[ds], S);
    }
    __builtin_amdgcn_s_setprio(0);

    // online softmax (base-2; Q pre-scaled by log2e/16); balanced max tree
    float p0 = fmaxf(S[0],S[8]),  p1 = fmaxf(S[1],S[9]);
    float p2 = fmaxf(S[2],S[10]), p3 = fmaxf(S[3],S[11]);
    float p4 = fmaxf(S[4],S[12]), p5 = fmaxf(S[5],S[13]);
    float p6 = fmaxf(S[6],S[14]), p7 = fmaxf(S[7],S[15]);
    p0 = fmaxf(p0,p4); p1 = fmaxf(p1,p5); p2 = fmaxf(p2,p6); p3 = fmaxf(p3,p7);
    float mx = fmaxf(fmaxf(p0,p1), fmaxf(p2,p3));
    { // cross-half max via permlane32_swap (VALU, no DS pipe)
      float mA = mx, mB = mx;
      asm("v_permlane32_swap_b32 %0, %1" : "+v"(mA), "+v"(mB));
      mx = fmaxf(mA, mB);
    }
    if (!__all(mx <= m + 11.5f)){
      float mn = fmaxf(m, mx);
      float al = exp2fast(m - mn);
      lsum *= al;
      #pragma unroll
      for(int dt=0;dt<8;dt++) o[dt] = o[dt] * al;
      m = mn;
    }
    unsigned pk[8];
    float rs = 0.f;
    #pragma unroll
    for(int tt=0;tt<8;tt++){
      float pa = exp2fast(S[2*tt]-m), pb = exp2fast(S[2*tt+1]-m);
      rs += pa + pb;
      unsigned pr;
      asm("v_cvt_pk_bf16_f32 %0, %1, %2" : "=v"(pr) : "v"(pa), "v"(pb));
      pk[tt] = pr;
    }
    { // cross-half sum via permlane32_swap
      float rA = rs, rB = rs;
      asm("v_permlane32_swap_b32 %0, %1" : "+v"(rA), "+v"(rB));
      lsum += rA + rB;
    }

    // PV: O^T[d][q] += V[d][j] * P[q][j]
    // F-fragments built via permlane32_swap: one swap yields both lo/hi words.
    __builtin_amdgcn_s_setprio(1);
    {
      unsigned a0 = pk[0], b0 = pk[2], a1 = pk[1], b1 = pk[3];
      asm("v_permlane32_swap_b32 %0, %1" : "+v"(a0), "+v"(b0));
      asm("v_permlane32_swap_b32 %0, %1" : "+v"(a1), "+v"(b1));
      union { unsigned u[4]; bf16x8 v; } F0;
      F0.u[0] = a0; F0.u[1] = a1; F0.u[2] = b0; F0.u[3] = b1;
      #pragma unroll
      for(int dt=0;dt<8;dt++){
        bf16x8 v0 = *(const bf16x8*)(lds + 16384 + (dt*32+lo5)*80 + hi*16);
        o[dt] = mfma32(v0, F0.v, o[dt]);
      }
    }
    {
      unsigned a0 = pk[4], b0 = pk[6], a1 = pk[5], b1 = pk[7];
      asm("v_permlane32_swap_b32 %0, %1" : "+v"(a0), "+v"(b0));
      asm("v_permlane32_swap_b32 %0, %1" : "+v"(a1), "+v"(b1));
      union { unsigned u[4]; bf16x8 v; } F1;
      F1.u[0] = a0; F1.u[1] = a1; F1.u[2] = b0; F1.u[3] = b1;
      #pragma unroll
      for(int dt=0;dt<8;dt++){
        bf16x8 v1 = *(const bf16x8*)(lds + 16384 + (dt*32+lo5)*80 + 32 + hi*16);
        o[dt] = mfma32(v1, F1.v, o[dt]);
      }
    }
    __builtin_amdgcn_s_setprio(0);
    __syncthreads();   // all reads done before next stage overwrites
  }

  // write unnormalized partial O (bf16) + (m, lsum)
  unsigned short* pb = (jh ? pO1 : pO0) + ((size_t)nb*HW_ + q0 + lo5)*C_;
  #pragma unroll
  for(int dt=0;dt<8;dt++){
    #pragma unroll
    for(int g=0;g<4;g++){
      int d0 = dt*32 + g*8 + hi*4;
      unsigned short h0 = f2bf(o[dt][4*g]);
      unsigned short h1 = f2bf(o[dt][4*g+1]);
      unsigned short h2 = f2bf(o[dt][4*g+2]);
      unsigned short h3 = f2bf(o[dt][4*g+3]);
      uint2 uo; uo.x = (unsigned)h0 | ((unsigned)h1<<16);
      uo.y = (unsigned)h2 | ((unsigned)h3<<16);
      *(uint2*)(pb + d0) = uo;
    }
  }
  if (l < 32){
    float2 ml; ml.x = m; ml.y = lsum;
    pml[(size_t)jh*32768 + (size_t)nb*HW_ + q0 + lo5] = ml;
  }
}

// ---------------- merge the two j-half partials (in place into pO0 = rest) ----------------
__global__ void k_merge(unsigned short* __restrict__ pO0,
                        const unsigned short* __restrict__ pO1,
                        const float2* __restrict__ pml){
  int t = threadIdx.x;
  int row = blockIdx.x*8 + (t>>5);
  int dn = t & 31;
  float2 ml0 = pml[row], ml1 = pml[32768 + row];
  float mN = fmaxf(ml0.x, ml1.x);
  float a0 = exp2fast(ml0.x - mN), a1 = exp2fast(ml1.x - mN);
  float inv = 1.f/(a0*ml0.y + a1*ml1.y);
  float s0 = a0*inv, s1 = a1*inv;
  size_t off = (size_t)row*256 + dn*8;
  uint4 u0 = *(const uint4*)(pO0 + off);
  uint4 u1 = *(const uint4*)(pO1 + off);
  unsigned r[4];
  unsigned w0[4] = {u0.x, u0.y, u0.z, u0.w};
  unsigned w1[4] = {u1.x, u1.y, u1.z, u1.w};
  #pragma unroll
  for(int q=0;q<4;q++){
    float lo = s0*bf2f((unsigned short)(w0[q]&0xffff)) + s1*bf2f((unsigned short)(w1[q]&0xffff));
    float hi = s0*bf2f((unsigned short)(w0[q]>>16))    + s1*bf2f((unsigned short)(w1[q]>>16));
    r[q] = (unsigned)f2bf(lo) | ((unsigned)f2bf(hi)<<16);
  }
  uint4 ru; ru.x=r[0]; ru.y=r[1]; ru.z=r[2]; ru.w=r[3];
  *(uint4*)(pO0 + off) = ru;
}

// ---------------- output projection + residual (fp32 out) ----------------
__global__ void k_outproj(const unsigned short* __restrict__ wob,
                          const unsigned short* __restrict__ rest,
                          const float* __restrict__ bo, const float* __restrict__ x,
                          float* __restrict__ out){
  int n = blockIdx.z;
  const unsigned short* B = rest + (size_t)n*HW_*C_;
  int t = threadIdx.x, w = t>>6, l = t&63, ri = l&15, k8 = (l>>4)*8;
  int row0 = blockIdx.x*64 + w*16;
  int col0 = blockIdx.y*64;
  f32x4 zero = {0.f,0.f,0.f,0.f};
  f32x4 acc[4] = {zero, zero, zero, zero};
  #pragma unroll
  for(int k=0;k<256;k+=32){
    bf16x8 a = *(const bf16x8*)(wob + (size_t)(row0+ri)*256 + k + k8);
    #pragma unroll
    for(int j=0;j<4;j++){
      bf16x8 b = *(const bf16x8*)(B + (size_t)(col0+j*16+ri)*256 + k + k8);
      acc[j] = mfma16(a,b,acc[j]);
    }
  }
  #pragma unroll
  for(int j=0;j<4;j++){
    #pragma unroll
    for(int r=0;r<4;r++){
      int row = row0 + (l>>4)*4 + r;
      int col = col0 + j*16 + ri;
      size_t idx = ((size_t)n*C_ + row)*HW_ + col;
      out[idx] = acc[j][r] + bo[row] + x[idx];
    }
  }
}

extern "C" void kernel_launch(void* const* d_in, const int* in_sizes, int n_in,
                              void* d_out, int out_size, void* d_ws, size_t ws_size,
                              hipStream_t stream) {
  const float* x   = (const float*)d_in[0];
  const float* lnw = (const float*)d_in[1];
  const float* lnb = (const float*)d_in[2];
  const float* wq  = (const float*)d_in[3];
  const float* bq  = (const float*)d_in[4];
  const float* wk  = (const float*)d_in[5];
  const float* bk  = (const float*)d_in[6];
  const float* wv  = (const float*)d_in[7];
  const float* bv  = (const float*)d_in[8];
  const float* wo  = (const float*)d_in[9];
  const float* bo  = (const float*)d_in[10];
  float* out = (float*)d_out;

  uintptr_t base = (uintptr_t)d_ws;
  float2* part  = (float2*)base;
  float2* stats = (float2*)(base + 16384);
  unsigned short* wqb = (unsigned short*)(base + 16448);
  unsigned short* wkb = wqb + 65536;
  unsigned short* wvb = wqb + 2*65536;
  unsigned short* wob = wqb + 3*65536;
  unsigned short* nx  = wqb + 4*65536;
  const size_t TEN = (size_t)N_*HW_*C_;
  unsigned short* qtb = nx + TEN;
  unsigned short* ktb = qtb + TEN;
  unsigned short* vvb = ktb + TEN;
  unsigned short* pO1 = vvb + TEN;                 // extra 16 MB partial (j-half 1)
  float2* pml = (float2*)(pO1 + TEN);              // 2*32768 float2
  unsigned short* rest = nx;                       // = pO0 (j-half 0), merged in place

  k_cvt<<<dim3(256),256,0,stream>>>(wq, wqb);
  k_cvt<<<dim3(256),256,0,stream>>>(wk, wkb);
  k_cvt<<<dim3(256),256,0,stream>>>(wv, wvb);
  k_cvt<<<dim3(256),256,0,stream>>>(wo, wob);

  k_stats1<<<dim3(2048),256,0,stream>>>(x, part);
  k_stats2<<<dim3(8),256,0,stream>>>(part, stats);
  k_norm<<<dim3(64,4,8),256,0,stream>>>(x, lnw, lnb, stats, nx);

  // Q pre-scaled by log2(e)/16 (softmax runs in base-2), K: [seq][dim]; V: [dim][seq]
  k_gemm<<<dim3(64,4,8),256,0,stream>>>(nx, (long)(HW_*C_), wqb, 0, bq, 0, 0.09016844f, qtb, (long)(HW_*C_), C_);
  k_gemm<<<dim3(64,4,8),256,0,stream>>>(nx, (long)(HW_*C_), wkb, 0, bk, 0, 1.0f, ktb, (long)(HW_*C_), C_);
  k_gemm<<<dim3(4,64,8),256,0,stream>>>(wvb, 0, nx, (long)(HW_*C_), bv, 1, 1.0f, vvb, (long)(C_*HW_), HW_);

  k_attn4<<<dim3(512),256,0,stream>>>(qtb, ktb, vvb, rest, pO1, pml);
  k_merge<<<dim3(4096),256,0,stream>>>(rest, pO1, pml);

  k_outproj<<<dim3(4,64,8),256,0,stream>>>(wob, rest, bo, x, out);
}